// Round 1
// baseline (2275.834 us; speedup 1.0000x reference)
//
#include <hip/hip_runtime.h>

#define B_ 2
#define S_ 2048
#define D_ 2048
#define H_ 16
#define HD_ 128
#define WIN_ 1024
#define M_ (B_*S_)      // 4096 rows (b*S+s)
#define N_ (H_*HD_)     // 2048

typedef unsigned short u16;
typedef __attribute__((ext_vector_type(8))) short short8;   // 8 bf16 (4 VGPRs)
typedef __attribute__((ext_vector_type(4))) float f32x4;    // MFMA C/D

__device__ __forceinline__ float b2f(u16 u) {
    union { unsigned int i; float f; } x; x.i = ((unsigned int)u) << 16; return x.f;
}
__device__ __forceinline__ u16 f2b(float f) {  // RNE
    union { float f; unsigned int i; } x; x.f = f;
    unsigned int u = x.i;
    return (u16)((u + 0x7fffu + ((u >> 16) & 1u)) >> 16);
}

// ---------------------------------------------------------------- cast fp32 -> bf16
__global__ __launch_bounds__(256) void cvt_kernel(const float* __restrict__ in,
                                                  u16* __restrict__ out, int n4) {
    int i = blockIdx.x * 256 + threadIdx.x;
    if (i >= n4) return;
    float4 v = ((const float4*)in)[i];
    ushort4 o;
    o.x = f2b(v.x); o.y = f2b(v.y); o.z = f2b(v.z); o.w = f2b(v.w);
    ((ushort4*)out)[i] = o;
}

// ---------------------------------------------------- transpose + cast: (R x C) fp32 -> (C x R) bf16
__global__ __launch_bounds__(256) void transpose_cvt_kernel(const float* __restrict__ in,
                                                            u16* __restrict__ out, int R, int C) {
    __shared__ float tile[32][33];
    int c0 = blockIdx.x * 32, r0 = blockIdx.y * 32;
    int tx = threadIdx.x & 31, ty = threadIdx.x >> 5;  // 32 x 8
#pragma unroll
    for (int rr = ty; rr < 32; rr += 8)
        tile[rr][tx] = in[(long)(r0 + rr) * C + c0 + tx];
    __syncthreads();
#pragma unroll
    for (int cc = ty; cc < 32; cc += 8)
        out[(long)(c0 + cc) * R + r0 + tx] = f2b(tile[tx][cc]);
}

// ---------------------------------------------------------------- bf16 MFMA GEMM, C = A * Bt^T
// A: (Mm x Kk) bf16 row-major. Bt: (Nn x Kk) bf16 row-major (i.e. B transposed).
// 128x128 block tile, 4 waves in 2x2, each wave 64x64 via 4x4 of 16x16x32 MFMA.
template <typename OutT>
__global__ __launch_bounds__(256) void gemm_bt_kernel(const u16* __restrict__ A,
                                                      const u16* __restrict__ Bt,
                                                      OutT* __restrict__ C,
                                                      int Mm, int Nn, int Kk) {
    constexpr int BK = 32;
    constexpr int LD = 40;  // 32 + 8 pad: 2-way LDS bank aliasing only (free)
    __shared__ u16 As[128 * LD];
    __shared__ u16 Bs[128 * LD];

    const int tid  = threadIdx.x;
    const int m0   = blockIdx.y * 128, n0 = blockIdx.x * 128;
    const int wid  = tid >> 6, lane = tid & 63;
    const int wm   = (wid >> 1) * 64, wn = (wid & 1) * 64;
    const int quad = lane >> 4, lrow = lane & 15;

    // loader mapping: 512 vec8 loads per tile; thread covers vec tid and tid+256
    const int r0  = tid >> 2;            // 0..63
    const int kc0 = (tid & 3) * 8;       // 0,8,16,24

    f32x4 acc[4][4];
#pragma unroll
    for (int a = 0; a < 4; ++a)
#pragma unroll
        for (int b = 0; b < 4; ++b) acc[a][b] = (f32x4)0.0f;

    for (int k0 = 0; k0 < Kk; k0 += BK) {
        uint4 av0 = *(const uint4*)&A [(long)(m0 + r0)      * Kk + k0 + kc0];
        uint4 av1 = *(const uint4*)&A [(long)(m0 + r0 + 64) * Kk + k0 + kc0];
        uint4 bv0 = *(const uint4*)&Bt[(long)(n0 + r0)      * Kk + k0 + kc0];
        uint4 bv1 = *(const uint4*)&Bt[(long)(n0 + r0 + 64) * Kk + k0 + kc0];
        __syncthreads();  // previous iteration's LDS reads done
        *(uint4*)&As[r0 * LD + kc0]        = av0;
        *(uint4*)&As[(r0 + 64) * LD + kc0] = av1;
        *(uint4*)&Bs[r0 * LD + kc0]        = bv0;
        *(uint4*)&Bs[(r0 + 64) * LD + kc0] = bv1;
        __syncthreads();

        short8 af[4], bf[4];
#pragma unroll
        for (int t = 0; t < 4; ++t)
            af[t] = *(const short8*)&As[(wm + t * 16 + lrow) * LD + quad * 8];
#pragma unroll
        for (int t = 0; t < 4; ++t)
            bf[t] = *(const short8*)&Bs[(wn + t * 16 + lrow) * LD + quad * 8];
#pragma unroll
        for (int tm = 0; tm < 4; ++tm)
#pragma unroll
            for (int tn = 0; tn < 4; ++tn)
                acc[tm][tn] = __builtin_amdgcn_mfma_f32_16x16x32_bf16(
                    af[tm], bf[tn], acc[tm][tn], 0, 0, 0);
    }

    // epilogue: D lane mapping col = lane&15, row = quad*4 + reg
#pragma unroll
    for (int tm = 0; tm < 4; ++tm)
#pragma unroll
        for (int tn = 0; tn < 4; ++tn) {
            int col  = n0 + wn + tn * 16 + lrow;
            int rowb = m0 + wm + tm * 16 + quad * 4;
#pragma unroll
            for (int r = 0; r < 4; ++r) {
                float v = acc[tm][tn][r];
                if constexpr (sizeof(OutT) == 2)
                    ((u16*)C)[(long)(rowb + r) * Nn + col] = f2b(v);
                else
                    ((float*)C)[(long)(rowb + r) * Nn + col] = v;
            }
        }
}

// ---------------------------------------------------------------- RMSNorm + RoPE, in place on (B,S,H,HD) bf16
__global__ __launch_bounds__(256) void norm_rope_kernel(u16* __restrict__ X,
                                                        const float* __restrict__ scale,
                                                        const float* __restrict__ cosp,
                                                        const float* __restrict__ sinp) {
    int wid = threadIdx.x >> 6, lane = threadIdx.x & 63;
    int row = blockIdx.x * 4 + wid;     // (b*S+s)*H + h, in [0, B*S*H)
    int bs  = row >> 4;                 // /H_  -> b*S+s
    long off = (long)row * HD_;
    float x1 = b2f(X[off + lane]);
    float x2 = b2f(X[off + lane + 64]);
    float ss = x1 * x1 + x2 * x2;
#pragma unroll
    for (int o = 1; o < 64; o <<= 1) ss += __shfl_xor(ss, o);
    float inv = rsqrtf(ss * (1.0f / HD_) + 1e-6f);
    long cb = (long)bs * HD_;
    float c1 = cosp[cb + lane],      s1 = sinp[cb + lane];
    float c2 = cosp[cb + lane + 64], s2 = sinp[cb + lane + 64];
    float n1 = scale[lane] * x1 * inv;
    float n2 = scale[lane + 64] * x2 * inv;
    X[off + lane]      = f2b(n1 * c1 - n2 * s1);   // first half: x*cos - x2*sin
    X[off + lane + 64] = f2b(n2 * c2 + n1 * s2);   // second half: x*cos + x1*sin
}

// ---------------------------------------------------------------- sliding-window attention, wave per query row
__global__ __launch_bounds__(256) void attn_kernel(const u16* __restrict__ Q,
                                                   const u16* __restrict__ K,
                                                   const u16* __restrict__ V,
                                                   u16* __restrict__ O) {
    __shared__ float sc[4][WIN_ + 1];
    __shared__ float qs[4][HD_];
    const int wid = threadIdx.x >> 6, lane = threadIdx.x & 63;
    const int gw = blockIdx.x * 4 + wid;   // ((b*H+h)*S + i)
    const int i  = gw & (S_ - 1);
    const int bh = gw >> 11;               // /S_
    const int h  = bh & (H_ - 1);
    const int b  = bh >> 4;

    const long qoff = ((long)(b * S_ + i) * H_ + h) * HD_;
    qs[wid][lane]      = b2f(Q[qoff + lane]);
    qs[wid][lane + 64] = b2f(Q[qoff + lane + 64]);
    __syncthreads();

    const int jlo = (i - WIN_ > 0) ? (i - WIN_) : 0;
    const int L   = i - jlo + 1;
    const float scale = 0.08838834764831845f;  // 128^-0.5
    const long kbase = ((long)(b * S_ + jlo) * H_ + h) * HD_;

    float mx = -1e30f;
    for (int jj = lane; jj < L; jj += 64) {
        const uint4* kp = (const uint4*)(K + kbase + (long)jj * (H_ * HD_));
        float acc = 0.f;
#pragma unroll
        for (int d8 = 0; d8 < 16; ++d8) {
            uint4 kv = kp[d8];
            int d = d8 * 8;
            acc += qs[wid][d + 0] * b2f((u16)(kv.x & 0xffff)) + qs[wid][d + 1] * b2f((u16)(kv.x >> 16));
            acc += qs[wid][d + 2] * b2f((u16)(kv.y & 0xffff)) + qs[wid][d + 3] * b2f((u16)(kv.y >> 16));
            acc += qs[wid][d + 4] * b2f((u16)(kv.z & 0xffff)) + qs[wid][d + 5] * b2f((u16)(kv.z >> 16));
            acc += qs[wid][d + 6] * b2f((u16)(kv.w & 0xffff)) + qs[wid][d + 7] * b2f((u16)(kv.w >> 16));
        }
        acc *= scale;
        sc[wid][jj] = acc;
        mx = fmaxf(mx, acc);
    }
#pragma unroll
    for (int o = 1; o < 64; o <<= 1) mx = fmaxf(mx, __shfl_xor(mx, o));
    __syncthreads();

    float sum = 0.f;
    for (int jj = lane; jj < L; jj += 64) {
        float p = __expf(sc[wid][jj] - mx);
        sc[wid][jj] = p;
        sum += p;
    }
#pragma unroll
    for (int o = 1; o < 64; o <<= 1) sum += __shfl_xor(sum, o);
    const float inv = 1.0f / sum;
    __syncthreads();

    // PV: lane owns d = 2*lane, 2*lane+1 (one dword of V per j)
    float o0 = 0.f, o1 = 0.f;
    const unsigned int* vp = (const unsigned int*)(V + kbase) + lane;
    for (int jj = 0; jj < L; ++jj) {
        float p = sc[wid][jj];
        unsigned int vv = vp[(long)jj * (H_ * HD_ / 2)];
        o0 += p * b2f((u16)(vv & 0xffff));
        o1 += p * b2f((u16)(vv >> 16));
    }
    long ooff = qoff + 2 * lane;
    O[ooff]     = f2b(o0 * inv);
    O[ooff + 1] = f2b(o1 * inv);
}

// ----------------------------------------------------------------
extern "C" void kernel_launch(void* const* d_in, const int* in_sizes, int n_in,
                              void* d_out, int out_size, void* d_ws, size_t ws_size,
                              hipStream_t stream) {
    const float* hs   = (const float*)d_in[0];
    const float* cosp = (const float*)d_in[1];
    const float* sinp = (const float*)d_in[2];
    const float* Wq   = (const float*)d_in[3];
    const float* Wk   = (const float*)d_in[4];
    const float* Wv   = (const float*)d_in[5];
    const float* Wo   = (const float*)d_in[6];
    const float* qsc  = (const float*)d_in[7];
    const float* ksc  = (const float*)d_in[8];
    float* out = (float*)d_out;

    char* ws = (char*)d_ws;
    const size_t MD = (size_t)M_ * D_;  // 8M elems
    const size_t WN = (size_t)D_ * N_;  // 4M elems
    u16* hsb = (u16*)ws;                 // 16 MB; reused as attention output later
    u16* Wqt = (u16*)(ws + MD * 2);
    u16* Wkt = Wqt + WN;
    u16* Wvt = Wkt + WN;
    u16* Wot = Wvt + WN;
    u16* Qb  = Wot + WN;
    u16* Kb  = Qb + MD;
    u16* Vb  = Kb + MD;
    u16* Ab  = hsb;  // overlay: hs_bf16 dead after QKV GEMMs

    cvt_kernel<<<(int)(MD / 4 / 256), 256, 0, stream>>>(hs, hsb, (int)(MD / 4));
    dim3 tg(64, 64);
    transpose_cvt_kernel<<<tg, 256, 0, stream>>>(Wq, Wqt, D_, N_);
    transpose_cvt_kernel<<<tg, 256, 0, stream>>>(Wk, Wkt, D_, N_);
    transpose_cvt_kernel<<<tg, 256, 0, stream>>>(Wv, Wvt, D_, N_);
    transpose_cvt_kernel<<<tg, 256, 0, stream>>>(Wo, Wot, N_, D_);

    dim3 gg(N_ / 128, M_ / 128);  // (16, 32)
    gemm_bt_kernel<u16><<<gg, 256, 0, stream>>>(hsb, Wqt, Qb, M_, N_, D_);
    gemm_bt_kernel<u16><<<gg, 256, 0, stream>>>(hsb, Wkt, Kb, M_, N_, D_);
    gemm_bt_kernel<u16><<<gg, 256, 0, stream>>>(hsb, Wvt, Vb, M_, N_, D_);

    norm_rope_kernel<<<B_ * S_ * H_ / 4, 256, 0, stream>>>(Qb, qsc, cosp, sinp);
    norm_rope_kernel<<<B_ * S_ * H_ / 4, 256, 0, stream>>>(Kb, ksc, cosp, sinp);

    attn_kernel<<<B_ * H_ * S_ / 4, 256, 0, stream>>>(Qb, Kb, Vb, Ab);

    dim3 gg2(D_ / 128, M_ / 128);
    gemm_bt_kernel<float><<<gg2, 256, 0, stream>>>(Ab, Wot, out, M_, D_, N_);
}

// Round 2
// 509.261 us; speedup vs baseline: 4.4689x; 4.4689x over previous
//
#include <hip/hip_runtime.h>

#define B_ 2
#define S_ 2048
#define D_ 2048
#define H_ 16
#define HD_ 128
#define WIN_ 1024
#define M_ (B_*S_)      // 4096 rows (b*S+s)
#define N_ (H_*HD_)     // 2048
#define SCALE_ 0.08838834764831845f

typedef unsigned short u16;
typedef __attribute__((ext_vector_type(8))) short short8;   // 8 bf16 (4 VGPRs)
typedef __attribute__((ext_vector_type(4))) float f32x4;    // MFMA C/D

__device__ __forceinline__ float b2f(u16 u) {
    union { unsigned int i; float f; } x; x.i = ((unsigned int)u) << 16; return x.f;
}
__device__ __forceinline__ u16 f2b(float f) {  // RNE
    union { float f; unsigned int i; } x; x.f = f;
    unsigned int u = x.i;
    return (u16)((u + 0x7fffu + ((u >> 16) & 1u)) >> 16);
}

// async global->LDS, 16B per lane; lds dest must be wave-uniform (HW adds lane*16)
__device__ __forceinline__ void async_ld16(const u16* g, u16* l) {
    __builtin_amdgcn_global_load_lds(
        (const __attribute__((address_space(1))) unsigned int*)g,
        (__attribute__((address_space(3))) unsigned int*)l, 16, 0, 0);
}

// ---------------------------------------------------------------- cast fp32 -> bf16
__global__ __launch_bounds__(256) void cvt_kernel(const float* __restrict__ in,
                                                  u16* __restrict__ out, int n4) {
    int i = blockIdx.x * 256 + threadIdx.x;
    if (i >= n4) return;
    float4 v = ((const float4*)in)[i];
    ushort4 o;
    o.x = f2b(v.x); o.y = f2b(v.y); o.z = f2b(v.z); o.w = f2b(v.w);
    ((ushort4*)out)[i] = o;
}

// ---------------------------------------------------- transpose + cast: (R x C) fp32 -> (C x R) bf16
__global__ __launch_bounds__(256) void transpose_cvt_kernel(const float* __restrict__ in,
                                                            u16* __restrict__ out, int R, int C) {
    __shared__ float tile[32][33];
    int c0 = blockIdx.x * 32, r0 = blockIdx.y * 32;
    int tx = threadIdx.x & 31, ty = threadIdx.x >> 5;  // 32 x 8
#pragma unroll
    for (int rr = ty; rr < 32; rr += 8)
        tile[rr][tx] = in[(long)(r0 + rr) * C + c0 + tx];
    __syncthreads();
#pragma unroll
    for (int cc = ty; cc < 32; cc += 8)
        out[(long)(c0 + cc) * R + r0 + tx] = f2b(tile[tx][cc]);
}

// ---------------------------------------------------------------- bf16 MFMA GEMM, C = A * Bt^T
// m97 structure: 128x128 tile, BK=32, global_load_lds width 16, unpadded LDS.
// MODE 0: fp32 row-major out. MODE 1: bf16 row-major out.
// MODE 2: bf16 out written V-transposed to (B,H,HD,S):  out[((b*H+h)*HD+d)*S + s]
template <int MODE>
__global__ __launch_bounds__(256) void gemm_bt_kernel(const u16* __restrict__ A,
                                                      const u16* __restrict__ Bt,
                                                      void* __restrict__ Cout,
                                                      int Mm, int Nn, int Kk) {
    __shared__ u16 As[128 * 32];
    __shared__ u16 Bs[128 * 32];

    const int tid  = threadIdx.x;
    const int m0   = blockIdx.y * 128, n0 = blockIdx.x * 128;
    const int wid  = tid >> 6, lane = tid & 63;
    const int wm   = (wid >> 1) * 64, wn = (wid & 1) * 64;
    const int quad = lane >> 4, lrow = lane & 15;
    const int lr4  = lane >> 2, lc8 = (lane & 3) * 8;  // staging: 4 lanes/row, 16B each

    f32x4 acc[4][4];
#pragma unroll
    for (int a = 0; a < 4; ++a)
#pragma unroll
        for (int b = 0; b < 4; ++b) acc[a][b] = (f32x4)0.0f;

    for (int k0 = 0; k0 < Kk; k0 += 32) {
        __syncthreads();  // previous tile's LDS reads done before overwrite
#pragma unroll
        for (int it = 0; it < 2; ++it) {
            const int ra = (wid + 4 * it) * 16;  // 16 rows per wave-issue
            async_ld16(&A [(long)(m0 + ra + lr4) * Kk + k0 + lc8], &As[ra * 32]);
            async_ld16(&Bt[(long)(n0 + ra + lr4) * Kk + k0 + lc8], &Bs[ra * 32]);
        }
        __syncthreads();  // drains vmcnt -> LDS visible

        short8 af[4], bf[4];
#pragma unroll
        for (int t = 0; t < 4; ++t)
            af[t] = *(const short8*)&As[(wm + t * 16 + lrow) * 32 + quad * 8];
#pragma unroll
        for (int t = 0; t < 4; ++t)
            bf[t] = *(const short8*)&Bs[(wn + t * 16 + lrow) * 32 + quad * 8];
#pragma unroll
        for (int tm = 0; tm < 4; ++tm)
#pragma unroll
            for (int tn = 0; tn < 4; ++tn)
                acc[tm][tn] = __builtin_amdgcn_mfma_f32_16x16x32_bf16(
                    af[tm], bf[tn], acc[tm][tn], 0, 0, 0);
    }

    // epilogue: D lane mapping col = lane&15, row = quad*4 + reg
#pragma unroll
    for (int tm = 0; tm < 4; ++tm)
#pragma unroll
        for (int tn = 0; tn < 4; ++tn) {
            const int col  = n0 + wn + tn * 16 + lrow;
            const int rowb = m0 + wm + tm * 16 + quad * 4;
            if constexpr (MODE == 2) {
                const int b = rowb >> 11, s = rowb & (S_ - 1);   // rows rowb..rowb+3 same b
                const int h = col >> 7, d = col & (HD_ - 1);
                ushort4 pk;
                pk.x = f2b(acc[tm][tn][0]); pk.y = f2b(acc[tm][tn][1]);
                pk.z = f2b(acc[tm][tn][2]); pk.w = f2b(acc[tm][tn][3]);
                *(ushort4*)&((u16*)Cout)[((long)((b * H_ + h) * HD_ + d)) * S_ + s] = pk;
            } else {
#pragma unroll
                for (int r = 0; r < 4; ++r) {
                    float v = acc[tm][tn][r];
                    if constexpr (MODE == 1)
                        ((u16*)Cout)[(long)(rowb + r) * Nn + col] = f2b(v);
                    else
                        ((float*)Cout)[(long)(rowb + r) * Nn + col] = v;
                }
            }
        }
}

// ---------------------------------------------------------------- RMSNorm + RoPE, in place on (B,S,H,HD) bf16
__global__ __launch_bounds__(256) void norm_rope_kernel(u16* __restrict__ X,
                                                        const float* __restrict__ scale,
                                                        const float* __restrict__ cosp,
                                                        const float* __restrict__ sinp) {
    int wid = threadIdx.x >> 6, lane = threadIdx.x & 63;
    int row = blockIdx.x * 4 + wid;     // (b*S+s)*H + h, in [0, B*S*H)
    int bs  = row >> 4;                 // /H_  -> b*S+s
    long off = (long)row * HD_;
    float x1 = b2f(X[off + lane]);
    float x2 = b2f(X[off + lane + 64]);
    float ss = x1 * x1 + x2 * x2;
#pragma unroll
    for (int o = 1; o < 64; o <<= 1) ss += __shfl_xor(ss, o);
    float inv = rsqrtf(ss * (1.0f / HD_) + 1e-6f);
    long cb = (long)bs * HD_;
    float c1 = cosp[cb + lane],      s1 = sinp[cb + lane];
    float c2 = cosp[cb + lane + 64], s2 = sinp[cb + lane + 64];
    float n1 = scale[lane] * x1 * inv;
    float n2 = scale[lane + 64] * x2 * inv;
    X[off + lane]      = f2b(n1 * c1 - n2 * s1);   // first half: x*cos - x2*sin
    X[off + lane + 64] = f2b(n2 * c2 + n1 * s2);   // second half: x*cos + x1*sin
}

// ---------------------------------------------------------------- MFMA flash attention, sliding window
// Block: (b,h) x 64 queries; 4 waves, each owns 16 query rows.
// Q (B,S,H,HD) bf16, K (B,S,H,HD) bf16 (normed+roped), Vt (B,H,HD,S) bf16.
// O written to (B,S,H*HD) bf16 for the final GEMM.
__global__ __launch_bounds__(256) void fattn_kernel(const u16* __restrict__ Q,
                                                    const u16* __restrict__ K,
                                                    const u16* __restrict__ Vt,
                                                    u16* __restrict__ O) {
    __shared__ u16 Ks[64][136];    // [key][d]   stride 272B: 16B-aligned, bank-rot 4 (free)
    __shared__ u16 Vs[128][88];    // [d][key]   stride 176B: 16B-aligned, bank-rot 12 (free)
    __shared__ u16 Ps[4][16][88];  // per wave [q][key]

    const int tid = threadIdx.x;
    const int wid = tid >> 6, lane = tid & 63;
    const int quad = lane >> 4, lrow = lane & 15;
    const int qb = blockIdx.x & 31;
    const int h  = (blockIdx.x >> 5) & (H_ - 1);
    const int b  = blockIdx.x >> 9;
    const int q0  = qb * 64;
    const int q0w = q0 + wid * 16;

    // Q A-frags: lane holds Q[q = q0w+lrow][d = c*32 + quad*8 .. +7]
    short8 qf[4];
    const long qrow = ((long)(b * S_ + q0w + lrow) * H_ + h) * HD_;
#pragma unroll
    for (int c = 0; c < 4; ++c)
        qf[c] = *(const short8*)&Q[qrow + c * 32 + quad * 8];

    float m_r[4], l_r[4];
    f32x4 oacc[8];
#pragma unroll
    for (int r = 0; r < 4; ++r) { m_r[r] = -1e30f; l_r[r] = 0.f; }
#pragma unroll
    for (int t = 0; t < 8; ++t) oacc[t] = (f32x4)0.0f;

    const int ktlo = (q0 - WIN_ > 0) ? (q0 - WIN_) : 0;   // 64-aligned
    const long kgbase = ((long)b * S_ * H_ + h) * HD_;
    const long vgbase = ((long)(b * H_ + h) * HD_) * S_;

    for (int kt0 = ktlo; kt0 < q0 + 64; kt0 += 64) {
        __syncthreads();  // previous tile's LDS reads done
#pragma unroll
        for (int it = 0; it < 4; ++it) {
            const int idx = it * 256 + tid;
            const int kr = idx >> 4, kc = (idx & 15) * 8;
            *(uint4*)&Ks[kr][kc] =
                *(const uint4*)&K[kgbase + (long)(kt0 + kr) * (H_ * HD_) + kc];
            const int vr = idx >> 3, vc = (idx & 7) * 8;
            *(uint4*)&Vs[vr][vc] =
                *(const uint4*)&Vt[vgbase + (long)vr * S_ + kt0 + vc];
        }
        __syncthreads();

        // scores: wave's 16 q rows x 64 keys
        f32x4 cs[4];
#pragma unroll
        for (int t = 0; t < 4; ++t) {
            cs[t] = (f32x4)0.0f;
#pragma unroll
            for (int c = 0; c < 4; ++c) {
                short8 kf = *(const short8*)&Ks[t * 16 + lrow][c * 32 + quad * 8];
                cs[t] = __builtin_amdgcn_mfma_f32_16x16x32_bf16(qf[c], kf, cs[t], 0, 0, 0);
            }
        }

        // mask (C layout: col = lane&15 -> key, row = quad*4+r -> query)
        const bool full = (kt0 + 63 <= q0w) && (kt0 >= q0w + 15 - WIN_);
        if (!full) {
#pragma unroll
            for (int t = 0; t < 4; ++t) {
                const int jc = kt0 + t * 16 + lrow;
#pragma unroll
                for (int r = 0; r < 4; ++r) {
                    const int i = q0w + quad * 4 + r;
                    if (jc > i || jc < i - WIN_) cs[t][r] = -1e30f;
                }
            }
        }

        // online softmax (SCALE folded into exp arg); row state replicated over quad's 16 lanes
        float mnew[4], alpha[4], rs[4];
#pragma unroll
        for (int r = 0; r < 4; ++r) {
            float v = fmaxf(fmaxf(cs[0][r], cs[1][r]), fmaxf(cs[2][r], cs[3][r]));
#pragma unroll
            for (int o = 1; o < 16; o <<= 1) v = fmaxf(v, __shfl_xor(v, o));
            mnew[r]  = fmaxf(m_r[r], v);
            alpha[r] = __expf((m_r[r] - mnew[r]) * SCALE_);
            m_r[r]   = mnew[r];
            rs[r]    = 0.f;
        }
#pragma unroll
        for (int t = 0; t < 4; ++t) {
#pragma unroll
            for (int r = 0; r < 4; ++r) {
                float p = __expf((cs[t][r] - mnew[r]) * SCALE_);
                rs[r] += p;
                Ps[wid][quad * 4 + r][t * 16 + lrow] = f2b(p);
            }
        }
#pragma unroll
        for (int r = 0; r < 4; ++r) {
            float v = rs[r];
#pragma unroll
            for (int o = 1; o < 16; o <<= 1) v += __shfl_xor(v, o);
            l_r[r] = l_r[r] * alpha[r] + v;
        }
#pragma unroll
        for (int t = 0; t < 8; ++t)
#pragma unroll
            for (int r = 0; r < 4; ++r) oacc[t][r] *= alpha[r];

        // PV: A-frag from Ps (same-wave RAW; compiler inserts lgkmcnt), B-frag from Vs rows (d)
        short8 pf0 = *(const short8*)&Ps[wid][lrow][quad * 8];
        short8 pf1 = *(const short8*)&Ps[wid][lrow][32 + quad * 8];
#pragma unroll
        for (int t = 0; t < 8; ++t) {
            short8 vf0 = *(const short8*)&Vs[t * 16 + lrow][quad * 8];
            short8 vf1 = *(const short8*)&Vs[t * 16 + lrow][32 + quad * 8];
            oacc[t] = __builtin_amdgcn_mfma_f32_16x16x32_bf16(pf0, vf0, oacc[t], 0, 0, 0);
            oacc[t] = __builtin_amdgcn_mfma_f32_16x16x32_bf16(pf1, vf1, oacc[t], 0, 0, 0);
        }
    }

    // epilogue: O[(b*S+q)*2048 + h*128 + d], q = q0w+quad*4+r, d = t*16+lrow
    float inv[4];
#pragma unroll
    for (int r = 0; r < 4; ++r) inv[r] = 1.0f / l_r[r];
#pragma unroll
    for (int t = 0; t < 8; ++t) {
        const int d = t * 16 + lrow;
#pragma unroll
        for (int r = 0; r < 4; ++r) {
            const int q = q0w + quad * 4 + r;
            O[(long)(b * S_ + q) * N_ + h * HD_ + d] = f2b(oacc[t][r] * inv[r]);
        }
    }
}

// ----------------------------------------------------------------
extern "C" void kernel_launch(void* const* d_in, const int* in_sizes, int n_in,
                              void* d_out, int out_size, void* d_ws, size_t ws_size,
                              hipStream_t stream) {
    const float* hs   = (const float*)d_in[0];
    const float* cosp = (const float*)d_in[1];
    const float* sinp = (const float*)d_in[2];
    const float* Wq   = (const float*)d_in[3];
    const float* Wk   = (const float*)d_in[4];
    const float* Wv   = (const float*)d_in[5];
    const float* Wo   = (const float*)d_in[6];
    const float* qsc  = (const float*)d_in[7];
    const float* ksc  = (const float*)d_in[8];
    float* out = (float*)d_out;

    char* ws = (char*)d_ws;
    const size_t MD = (size_t)M_ * D_;  // 8M elems
    const size_t WN = (size_t)D_ * N_;  // 4M elems
    u16* hsb = (u16*)ws;                 // 16 MB; reused as attention output later
    u16* Wqt = (u16*)(ws + MD * 2);
    u16* Wkt = Wqt + WN;
    u16* Wvt = Wkt + WN;
    u16* Wot = Wvt + WN;
    u16* Qb  = Wot + WN;
    u16* Kb  = Qb + MD;
    u16* Vtb = Kb + MD;                  // V transposed (B,H,HD,S)
    u16* Ab  = hsb;                      // overlay: hs_bf16 dead after QKV GEMMs

    cvt_kernel<<<(int)(MD / 4 / 256), 256, 0, stream>>>(hs, hsb, (int)(MD / 4));
    dim3 tg(64, 64);
    transpose_cvt_kernel<<<tg, 256, 0, stream>>>(Wq, Wqt, D_, N_);
    transpose_cvt_kernel<<<tg, 256, 0, stream>>>(Wk, Wkt, D_, N_);
    transpose_cvt_kernel<<<tg, 256, 0, stream>>>(Wv, Wvt, D_, N_);
    transpose_cvt_kernel<<<tg, 256, 0, stream>>>(Wo, Wot, N_, D_);

    dim3 gg(N_ / 128, M_ / 128);  // (16, 32)
    gemm_bt_kernel<1><<<gg, 256, 0, stream>>>(hsb, Wqt, Qb,  M_, N_, D_);
    gemm_bt_kernel<1><<<gg, 256, 0, stream>>>(hsb, Wkt, Kb,  M_, N_, D_);
    gemm_bt_kernel<2><<<gg, 256, 0, stream>>>(hsb, Wvt, Vtb, M_, N_, D_);

    norm_rope_kernel<<<B_ * S_ * H_ / 4, 256, 0, stream>>>(Qb, qsc, cosp, sinp);
    norm_rope_kernel<<<B_ * S_ * H_ / 4, 256, 0, stream>>>(Kb, ksc, cosp, sinp);

    fattn_kernel<<<B_ * H_ * (S_ / 64), 256, 0, stream>>>(Qb, Kb, Vtb, Ab);

    dim3 gg2(D_ / 128, M_ / 128);
    gemm_bt_kernel<0><<<gg2, 256, 0, stream>>>(Ab, Wot, out, M_, D_, N_);
}

// Round 3
// 421.276 us; speedup vs baseline: 5.4022x; 1.2089x over previous
//
#include <hip/hip_runtime.h>

#define B_ 2
#define S_ 2048
#define D_ 2048
#define H_ 16
#define HD_ 128
#define WIN_ 1024
#define M_ (B_*S_)      // 4096 rows (b*S+s)
#define N_ (H_*HD_)     // 2048
#define SCALE_ 0.08838834764831845f
#define CSHIFT_ 11.5f   // fixed softmax shift: scores*SCALE <= 128*SCALE = 11.31 (rows RMS-normed, RoPE norm-preserving)

typedef unsigned short u16;
typedef __attribute__((ext_vector_type(8))) short short8;   // 8 bf16 (4 VGPRs)
typedef __attribute__((ext_vector_type(4))) float f32x4;    // MFMA C/D

__device__ __forceinline__ float b2f(u16 u) {
    union { unsigned int i; float f; } x; x.i = ((unsigned int)u) << 16; return x.f;
}
__device__ __forceinline__ u16 f2b(float f) {  // RNE
    union { float f; unsigned int i; } x; x.f = f;
    unsigned int u = x.i;
    return (u16)((u + 0x7fffu + ((u >> 16) & 1u)) >> 16);
}

// async global->LDS, 16B per lane; lds dest wave-uniform base (HW adds lane*16)
__device__ __forceinline__ void async_ld16(const u16* g, u16* l) {
    __builtin_amdgcn_global_load_lds(
        (const __attribute__((address_space(1))) unsigned int*)g,
        (__attribute__((address_space(3))) unsigned int*)l, 16, 0, 0);
}

// ---------------------------------------------------------------- cast fp32 -> bf16
__global__ __launch_bounds__(256) void cvt_kernel(const float* __restrict__ in,
                                                  u16* __restrict__ out, int n4) {
    int i = blockIdx.x * 256 + threadIdx.x;
    if (i >= n4) return;
    float4 v = ((const float4*)in)[i];
    ushort4 o;
    o.x = f2b(v.x); o.y = f2b(v.y); o.z = f2b(v.z); o.w = f2b(v.w);
    ((ushort4*)out)[i] = o;
}

// ------------------------------------------- 4x transpose+cast 2048x2048 fp32 -> bf16 in one launch
__global__ __launch_bounds__(256) void transpose4_kernel(const float* __restrict__ W0, const float* __restrict__ W1,
                                                         const float* __restrict__ W2, const float* __restrict__ W3,
                                                         u16* __restrict__ O0, u16* __restrict__ O1,
                                                         u16* __restrict__ O2, u16* __restrict__ O3) {
    __shared__ float tile[32][33];
    const float* in; u16* out;
    switch (blockIdx.z) {
        case 0: in = W0; out = O0; break;
        case 1: in = W1; out = O1; break;
        case 2: in = W2; out = O2; break;
        default: in = W3; out = O3; break;
    }
    const int C = 2048, R = 2048;
    int c0 = blockIdx.x * 32, r0 = blockIdx.y * 32;
    int tx = threadIdx.x & 31, ty = threadIdx.x >> 5;  // 32 x 8
#pragma unroll
    for (int rr = ty; rr < 32; rr += 8)
        tile[rr][tx] = in[(long)(r0 + rr) * C + c0 + tx];
    __syncthreads();
#pragma unroll
    for (int cc = ty; cc < 32; cc += 8)
        out[(long)(c0 + cc) * R + r0 + tx] = f2b(tile[tx][cc]);
}

// ---------------------------------------------------------------- GEMM core macro-shared pieces
// m97 structure: 128x128 tile, BK=32, global_load_lds width 16, unpadded LDS.

// Merged QKV GEMM: A (4096 x 2048) bf16, Bt3 (6144 x 2048) bf16 = [Wq^T; Wk^T; Wv^T].
// Epilogue: seg 0 -> Qb row-major, seg 1 -> Kb row-major, seg 2 -> Vtb (B,H,HD,S) transposed.
__global__ __launch_bounds__(256) void gemm_qkv_kernel(const u16* __restrict__ A,
                                                       const u16* __restrict__ Bt3,
                                                       u16* __restrict__ Qb,
                                                       u16* __restrict__ Kb,
                                                       u16* __restrict__ Vtb) {
    constexpr int Kk = 2048;
    __shared__ u16 As[128 * 32];
    __shared__ u16 Bs[128 * 32];

    const int tid  = threadIdx.x;
    const int m0   = blockIdx.y * 128, n0 = blockIdx.x * 128;
    const int wid  = tid >> 6, lane = tid & 63;
    const int wm   = (wid >> 1) * 64, wn = (wid & 1) * 64;
    const int quad = lane >> 4, lrow = lane & 15;
    const int lr4  = lane >> 2, lc8 = (lane & 3) * 8;

    f32x4 acc[4][4];
#pragma unroll
    for (int a = 0; a < 4; ++a)
#pragma unroll
        for (int b = 0; b < 4; ++b) acc[a][b] = (f32x4)0.0f;

    for (int k0 = 0; k0 < Kk; k0 += 32) {
        __syncthreads();
#pragma unroll
        for (int it = 0; it < 2; ++it) {
            const int ra = (wid + 4 * it) * 16;
            async_ld16(&A  [(long)(m0 + ra + lr4) * Kk + k0 + lc8], &As[ra * 32]);
            async_ld16(&Bt3[(long)(n0 + ra + lr4) * Kk + k0 + lc8], &Bs[ra * 32]);
        }
        __syncthreads();

        short8 af[4], bf[4];
#pragma unroll
        for (int t = 0; t < 4; ++t)
            af[t] = *(const short8*)&As[(wm + t * 16 + lrow) * 32 + quad * 8];
#pragma unroll
        for (int t = 0; t < 4; ++t)
            bf[t] = *(const short8*)&Bs[(wn + t * 16 + lrow) * 32 + quad * 8];
#pragma unroll
        for (int tm = 0; tm < 4; ++tm)
#pragma unroll
            for (int tn = 0; tn < 4; ++tn)
                acc[tm][tn] = __builtin_amdgcn_mfma_f32_16x16x32_bf16(
                    af[tm], bf[tn], acc[tm][tn], 0, 0, 0);
    }

    const int seg = n0 >> 11;  // block-uniform: 0=Q, 1=K, 2=V
#pragma unroll
    for (int tm = 0; tm < 4; ++tm)
#pragma unroll
        for (int tn = 0; tn < 4; ++tn) {
            const int colg = (n0 & 2047) + wn + tn * 16 + lrow;
            const int rowb = m0 + wm + tm * 16 + quad * 4;
            if (seg == 2) {
                const int b = rowb >> 11, s = rowb & (S_ - 1);
                const int h = colg >> 7, d = colg & (HD_ - 1);
                ushort4 pk;
                pk.x = f2b(acc[tm][tn][0]); pk.y = f2b(acc[tm][tn][1]);
                pk.z = f2b(acc[tm][tn][2]); pk.w = f2b(acc[tm][tn][3]);
                *(ushort4*)&Vtb[((long)((b * H_ + h) * HD_ + d)) * S_ + s] = pk;
            } else {
                u16* dst = (seg == 0) ? Qb : Kb;
#pragma unroll
                for (int r = 0; r < 4; ++r)
                    dst[(long)(rowb + r) * N_ + colg] = f2b(acc[tm][tn][r]);
            }
        }
}

// Final projection GEMM: fp32 row-major out.
__global__ __launch_bounds__(256) void gemm_out_kernel(const u16* __restrict__ A,
                                                       const u16* __restrict__ Bt,
                                                       float* __restrict__ C) {
    constexpr int Kk = 2048, Nn = 2048;
    __shared__ u16 As[128 * 32];
    __shared__ u16 Bs[128 * 32];

    const int tid  = threadIdx.x;
    const int m0   = blockIdx.y * 128, n0 = blockIdx.x * 128;
    const int wid  = tid >> 6, lane = tid & 63;
    const int wm   = (wid >> 1) * 64, wn = (wid & 1) * 64;
    const int quad = lane >> 4, lrow = lane & 15;
    const int lr4  = lane >> 2, lc8 = (lane & 3) * 8;

    f32x4 acc[4][4];
#pragma unroll
    for (int a = 0; a < 4; ++a)
#pragma unroll
        for (int b = 0; b < 4; ++b) acc[a][b] = (f32x4)0.0f;

    for (int k0 = 0; k0 < Kk; k0 += 32) {
        __syncthreads();
#pragma unroll
        for (int it = 0; it < 2; ++it) {
            const int ra = (wid + 4 * it) * 16;
            async_ld16(&A [(long)(m0 + ra + lr4) * Kk + k0 + lc8], &As[ra * 32]);
            async_ld16(&Bt[(long)(n0 + ra + lr4) * Kk + k0 + lc8], &Bs[ra * 32]);
        }
        __syncthreads();

        short8 af[4], bf[4];
#pragma unroll
        for (int t = 0; t < 4; ++t)
            af[t] = *(const short8*)&As[(wm + t * 16 + lrow) * 32 + quad * 8];
#pragma unroll
        for (int t = 0; t < 4; ++t)
            bf[t] = *(const short8*)&Bs[(wn + t * 16 + lrow) * 32 + quad * 8];
#pragma unroll
        for (int tm = 0; tm < 4; ++tm)
#pragma unroll
            for (int tn = 0; tn < 4; ++tn)
                acc[tm][tn] = __builtin_amdgcn_mfma_f32_16x16x32_bf16(
                    af[tm], bf[tn], acc[tm][tn], 0, 0, 0);
    }

#pragma unroll
    for (int tm = 0; tm < 4; ++tm)
#pragma unroll
        for (int tn = 0; tn < 4; ++tn) {
            const int col  = n0 + wn + tn * 16 + lrow;
            const int rowb = m0 + wm + tm * 16 + quad * 4;
#pragma unroll
            for (int r = 0; r < 4; ++r)
                C[(long)(rowb + r) * Nn + col] = acc[tm][tn][r];
        }
}

// ---------------------------------------------------------------- RMSNorm + RoPE, in place on (B,S,H,HD) bf16
__global__ __launch_bounds__(256) void norm_rope_kernel(u16* __restrict__ X,
                                                        const float* __restrict__ scale,
                                                        const float* __restrict__ cosp,
                                                        const float* __restrict__ sinp) {
    int wid = threadIdx.x >> 6, lane = threadIdx.x & 63;
    int row = blockIdx.x * 4 + wid;     // (b*S+s)*H + h
    int bs  = row >> 4;                 // /H_
    long off = (long)row * HD_;
    float x1 = b2f(X[off + lane]);
    float x2 = b2f(X[off + lane + 64]);
    float ss = x1 * x1 + x2 * x2;
#pragma unroll
    for (int o = 1; o < 64; o <<= 1) ss += __shfl_xor(ss, o);
    float inv = rsqrtf(ss * (1.0f / HD_) + 1e-6f);
    long cb = (long)bs * HD_;
    float c1 = cosp[cb + lane],      s1 = sinp[cb + lane];
    float c2 = cosp[cb + lane + 64], s2 = sinp[cb + lane + 64];
    float n1 = scale[lane] * x1 * inv;
    float n2 = scale[lane + 64] * x2 * inv;
    X[off + lane]      = f2b(n1 * c1 - n2 * s1);
    X[off + lane + 64] = f2b(n2 * c2 + n1 * s2);
}

// ---------------------------------------------------------------- MFMA flash attention v2
// Block: (b,h) x 128 queries; 8 waves x 16 q rows. 64-key tiles.
// Fixed-shift softmax (no online max/rescale). K/V staged via global_load_lds
// with XOR chunk swizzle (16B chunks, chunk ^= row&7) over unpadded strides.
__global__ __launch_bounds__(512, 4) void fattn_kernel(const u16* __restrict__ Q,
                                                       const u16* __restrict__ K,
                                                       const u16* __restrict__ Vt,
                                                       u16* __restrict__ O) {
    __shared__ u16 Ks[64 * 128];      // [key][d-chunk swizzled], 256B rows
    __shared__ u16 Vs[128 * 64];      // [d][key-chunk swizzled], 128B rows
    __shared__ u16 Ps[8][16 * 72];    // per-wave [q][key], stride 144B (16B-aligned)

    const int tid  = threadIdx.x;
    const int wid  = tid >> 6, lane = tid & 63;
    const int quad = lane >> 4, lrow = lane & 15;
    const int qb = 15 - (blockIdx.x & 15);          // heavy blocks first
    const int h  = (blockIdx.x >> 4) & (H_ - 1);
    const int b  = blockIdx.x >> 8;
    const int q0  = qb * 128;
    const int q0w = q0 + wid * 16;

    // Q A-frags: lane holds Q[q=q0w+lrow][d = c*32 + quad*8 .. +7]
    short8 qf[4];
    const long qrow = ((long)(b * S_ + q0w + lrow) * H_ + h) * HD_;
#pragma unroll
    for (int c = 0; c < 4; ++c)
        qf[c] = *(const short8*)&Q[qrow + c * 32 + quad * 8];

    float l_r[4] = {0.f, 0.f, 0.f, 0.f};
    f32x4 oacc[8];
#pragma unroll
    for (int t = 0; t < 8; ++t) oacc[t] = (f32x4)0.0f;

    const int ktlo = (q0 - WIN_ > 0) ? (q0 - WIN_) : 0;   // 64-aligned
    const long kgbase = ((long)b * S_ * H_ + h) * HD_;
    const long vgbase = ((long)(b * H_ + h) * HD_) * S_;
    const int lxor = lrow & 7;

    for (int kt0 = ktlo; kt0 < q0 + 128; kt0 += 64) {
        __syncthreads();  // previous tile's LDS reads done
        // stage K tile: 64 rows x 256B; 2 issues/wave, 4 rows each
#pragma unroll
        for (int it = 0; it < 2; ++it) {
            const int rb = (wid * 2 + it) * 4;
            const int row = rb + (lane >> 4);
            const int cg = (lane & 15) ^ (row & 7);
            async_ld16(&K[kgbase + (long)(kt0 + row) * (H_ * HD_) + cg * 8], &Ks[rb * 128]);
        }
        // stage V tile: 128 d-rows x 128B; 2 issues/wave, 8 rows each
#pragma unroll
        for (int it = 0; it < 2; ++it) {
            const int db = (wid * 2 + it) * 8;
            const int d = db + (lane >> 3);
            const int cg = (lane & 7) ^ (d & 7);
            async_ld16(&Vt[vgbase + (long)d * S_ + kt0 + cg * 8], &Vs[db * 64]);
        }
        __syncthreads();  // drains vmcnt

        const bool active = (kt0 <= q0w + 15) && (kt0 + 63 >= q0w - WIN_);
        if (active) {
            // scores: wave's 16 q rows x 64 keys
            f32x4 cs[4];
#pragma unroll
            for (int t = 0; t < 4; ++t) {
                cs[t] = (f32x4)0.0f;
                const int krow = (t * 16 + lrow) * 128;
#pragma unroll
                for (int c = 0; c < 4; ++c) {
                    short8 kf = *(const short8*)&Ks[krow + (((c * 4 + quad) ^ lxor) * 8)];
                    cs[t] = __builtin_amdgcn_mfma_f32_16x16x32_bf16(qf[c], kf, cs[t], 0, 0, 0);
                }
            }

            // mask (C layout: col=lane&15 -> key, row=quad*4+r -> query)
            const bool full = (kt0 + 63 <= q0w) && (kt0 >= q0w + 15 - WIN_);
            if (!full) {
#pragma unroll
                for (int t = 0; t < 4; ++t) {
                    const int jc = kt0 + t * 16 + lrow;
#pragma unroll
                    for (int r = 0; r < 4; ++r) {
                        const int i = q0w + quad * 4 + r;
                        if (jc > i || jc < i - WIN_) cs[t][r] = -1e30f;
                    }
                }
            }

            // p = exp(s*SCALE - C); accumulate l per-lane (reduced once at end)
#pragma unroll
            for (int t = 0; t < 4; ++t)
#pragma unroll
                for (int r = 0; r < 4; ++r) {
                    float p = __expf(fmaf(cs[t][r], SCALE_, -CSHIFT_));
                    l_r[r] += p;
                    Ps[wid][(quad * 4 + r) * 72 + t * 16 + lrow] = f2b(p);
                }

            // PV: A-frag from Ps (same-wave RAW), B-frag from swizzled Vs
            short8 pf0 = *(const short8*)&Ps[wid][lrow * 72 + quad * 8];
            short8 pf1 = *(const short8*)&Ps[wid][lrow * 72 + 32 + quad * 8];
#pragma unroll
            for (int t = 0; t < 8; ++t) {
                const int vrow = (t * 16 + lrow) * 64;
                short8 vf0 = *(const short8*)&Vs[vrow + ((quad ^ lxor) * 8)];
                short8 vf1 = *(const short8*)&Vs[vrow + (((quad + 4) ^ lxor) * 8)];
                oacc[t] = __builtin_amdgcn_mfma_f32_16x16x32_bf16(pf0, vf0, oacc[t], 0, 0, 0);
                oacc[t] = __builtin_amdgcn_mfma_f32_16x16x32_bf16(pf1, vf1, oacc[t], 0, 0, 0);
            }
        }
    }

    // l: reduce over the 16 lrow lanes (row set is per-quad, so xor<16 only)
    float inv[4];
#pragma unroll
    for (int r = 0; r < 4; ++r) {
        float v = l_r[r];
#pragma unroll
        for (int o = 1; o < 16; o <<= 1) v += __shfl_xor(v, o);
        inv[r] = 1.0f / v;
    }

    // epilogue: O[(b*S+q)*2048 + h*128 + d], q = q0w+quad*4+r, d = t*16+lrow
#pragma unroll
    for (int t = 0; t < 8; ++t) {
        const int d = t * 16 + lrow;
#pragma unroll
        for (int r = 0; r < 4; ++r) {
            const int q = q0w + quad * 4 + r;
            O[(long)(b * S_ + q) * N_ + h * HD_ + d] = f2b(oacc[t][r] * inv[r]);
        }
    }
}

// ----------------------------------------------------------------
extern "C" void kernel_launch(void* const* d_in, const int* in_sizes, int n_in,
                              void* d_out, int out_size, void* d_ws, size_t ws_size,
                              hipStream_t stream) {
    const float* hs   = (const float*)d_in[0];
    const float* cosp = (const float*)d_in[1];
    const float* sinp = (const float*)d_in[2];
    const float* Wq   = (const float*)d_in[3];
    const float* Wk   = (const float*)d_in[4];
    const float* Wv   = (const float*)d_in[5];
    const float* Wo   = (const float*)d_in[6];
    const float* qsc  = (const float*)d_in[7];
    const float* ksc  = (const float*)d_in[8];
    float* out = (float*)d_out;

    char* ws = (char*)d_ws;
    const size_t MD = (size_t)M_ * D_;  // 8M elems
    const size_t WN = (size_t)D_ * N_;  // 4M elems
    u16* hsb = (u16*)ws;                 // reused as attention output later
    u16* Wqt = (u16*)(ws + MD * 2);      // Wqt/Wkt/Wvt contiguous -> one 6144-row B
    u16* Wkt = Wqt + WN;
    u16* Wvt = Wkt + WN;
    u16* Wot = Wvt + WN;
    u16* Qb  = Wot + WN;
    u16* Kb  = Qb + MD;
    u16* Vtb = Kb + MD;                  // V transposed (B,H,HD,S)
    u16* Ab  = hsb;

    cvt_kernel<<<(int)(MD / 4 / 256), 256, 0, stream>>>(hs, hsb, (int)(MD / 4));
    dim3 tg(64, 64, 4);
    transpose4_kernel<<<tg, 256, 0, stream>>>(Wq, Wk, Wv, Wo, Wqt, Wkt, Wvt, Wot);

    dim3 gqkv(48, 32);  // N=6144
    gemm_qkv_kernel<<<gqkv, 256, 0, stream>>>(hsb, Wqt, Qb, Kb, Vtb);

    norm_rope_kernel<<<B_ * S_ * H_ / 4, 256, 0, stream>>>(Qb, qsc, cosp, sinp);
    norm_rope_kernel<<<B_ * S_ * H_ / 4, 256, 0, stream>>>(Kb, ksc, cosp, sinp);

    fattn_kernel<<<B_ * H_ * (S_ / 128), 512, 0, stream>>>(Qb, Kb, Vtb, Ab);

    dim3 gout(16, 32);
    gemm_out_kernel<<<gout, 256, 0, stream>>>(Ab, Wot, out);
}